// Round 1
// baseline (233.203 us; speedup 1.0000x reference)
//
#include <hip/hip_runtime.h>

// LatticeCrf log_prob on MI355X.
// Strategy: linear-space chunked scan.
//   denom: alpha_T = exp(w_init)^T * prod_t exp(step_t).  Split T into C chunks;
//   kernel1 computes per-chunk 32x32 products M_c = prod exp(step_t) * 2^-6/step
//   (fp32, V^3 MACs per step via LDS-tiled VALU FMA). kernel2 combines:
//   a <- a*M_c with per-chunk renorm, plus the numerator gather.
#define BB 64
#define TT 512
#define VV 32
#define CC 8
#define LL (TT / CC)          // 64 steps per chunk
#define MSTRIDE 40            // padded row stride for M in LDS (2-way conflicts only)
#define SHIFT 6.0f            // E scaled by 2^-SHIFT per step; add back SHIFT*T*ln2 at end
#define LOG2E 1.4426950408889634f
#define LN2f 0.6931471805599453f

__global__ __launch_bounds__(256) void crf_chunk_kernel(
    const float* __restrict__ scores,
    const float* __restrict__ w_tx,
    const float* __restrict__ w_dur,
    float* __restrict__ ws_M)
{
    __shared__ float Mlds[2][VV * MSTRIDE];
    __shared__ float Elds[VV * VV];

    const int tid = threadIdx.x;
    const int bc  = blockIdx.x;          // b*CC + c
    const int r   = tid >> 3;            // 0..31  (output row)
    const int j0  = (tid & 7) * 4;       // 0,4,...,28 (output col group)

    // This thread builds E elements [r][j0..j0+3] every step; preload w terms.
    const int widx = r * VV + j0;
    const float4 wtx4 = *(const float4*)(w_tx + widx);
    const float4 wdr4 = *(const float4*)(w_dur + widx);
    float4 w2;
    w2.x = (wtx4.x + wdr4.x) * LOG2E - SHIFT;
    w2.y = (wtx4.y + wdr4.y) * LOG2E - SHIFT;
    w2.z = (wtx4.z + wdr4.z) * LOG2E - SHIFT;
    w2.w = (wtx4.w + wdr4.w) * LOG2E - SHIFT;

    // init M = I in buf 0
    float4 id;
    id.x = (r == j0 + 0) ? 1.f : 0.f;
    id.y = (r == j0 + 1) ? 1.f : 0.f;
    id.z = (r == j0 + 2) ? 1.f : 0.f;
    id.w = (r == j0 + 3) ? 1.f : 0.f;
    *(float4*)&Mlds[0][r * MSTRIDE + j0] = id;

    const int b = bc >> 3, c = bc & 7;
    const float* sc = scores + ((size_t)b * TT + (size_t)c * LL) * (VV * VV);

    // build E_0
    {
        float4 s = *(const float4*)(sc + tid * 4);
        float4 e;
        e.x = __builtin_amdgcn_exp2f(__builtin_fmaf(s.x, LOG2E, w2.x));
        e.y = __builtin_amdgcn_exp2f(__builtin_fmaf(s.y, LOG2E, w2.y));
        e.z = __builtin_amdgcn_exp2f(__builtin_fmaf(s.z, LOG2E, w2.z));
        e.w = __builtin_amdgcn_exp2f(__builtin_fmaf(s.w, LOG2E, w2.w));
        *(float4*)&Elds[tid * 4] = e;
    }
    __syncthreads();

    int p = 0;
    for (int t = 0; t < LL; ++t) {
        // prefetch next step's scores into registers
        float4 snext;
        if (t + 1 < LL)
            snext = *(const float4*)(sc + (size_t)(t + 1) * (VV * VV) + tid * 4);

        // MAC: M_new[r][j0..3] = sum_i M[r][i] * E[i][j0..3]
        float4 acc = make_float4(0.f, 0.f, 0.f, 0.f);
        const float* Mrow = &Mlds[p][r * MSTRIDE];
        #pragma unroll
        for (int i = 0; i < VV; ++i) {
            const float  m = Mrow[i];                         // broadcast b32
            const float4 e = *(const float4*)&Elds[i * VV + j0]; // b128
            acc.x = __builtin_fmaf(m, e.x, acc.x);
            acc.y = __builtin_fmaf(m, e.y, acc.y);
            acc.z = __builtin_fmaf(m, e.z, acc.z);
            acc.w = __builtin_fmaf(m, e.w, acc.w);
        }
        *(float4*)&Mlds[1 - p][r * MSTRIDE + j0] = acc;
        __syncthreads();   // M_new visible; everyone done reading Elds

        if (t + 1 < LL) {
            float4 e;
            e.x = __builtin_amdgcn_exp2f(__builtin_fmaf(snext.x, LOG2E, w2.x));
            e.y = __builtin_amdgcn_exp2f(__builtin_fmaf(snext.y, LOG2E, w2.y));
            e.z = __builtin_amdgcn_exp2f(__builtin_fmaf(snext.z, LOG2E, w2.z));
            e.w = __builtin_amdgcn_exp2f(__builtin_fmaf(snext.w, LOG2E, w2.w));
            *(float4*)&Elds[tid * 4] = e;
        }
        p ^= 1;
        __syncthreads();   // E_{t+1} visible
    }

    // write out chunk matrix
    float* outM = ws_M + (size_t)bc * (VV * VV);
    *(float4*)(outM + r * VV + j0) = *(float4*)&Mlds[p][r * MSTRIDE + j0];
}

__global__ __launch_bounds__(64) void crf_combine_kernel(
    const float* __restrict__ scores,
    const int*   __restrict__ targets,
    const float* __restrict__ w_tx,
    const float* __restrict__ w_init,
    const float* __restrict__ w_final,
    const float* __restrict__ w_dur,
    const float* __restrict__ ws_M,
    float* __restrict__ out)
{
    const int b    = blockIdx.x;
    const int lane = threadIdx.x;   // 0..63

    // ---- numerator: sum_t (scores[b,t,src,dst] + w_tx + w_dur) ----
    const int* tg = targets + b * (TT + 1);
    float num = 0.f;
    #pragma unroll
    for (int k = 0; k < TT / 64; ++k) {
        const int t  = lane + 64 * k;
        const int s_ = tg[t];
        const int d_ = tg[t + 1];
        const int wi = s_ * VV + d_;
        num += scores[(((size_t)b * TT + t) * VV + s_) * VV + d_] + w_tx[wi] + w_dur[wi];
    }
    #pragma unroll
    for (int m = 32; m >= 1; m >>= 1) num += __shfl_xor(num, m, 64);

    // ---- denominator: a = exp(w_init); a <- a * M_c (renorm each chunk) ----
    const int j = lane & 31;
    float a    = __builtin_amdgcn_exp2f(w_init[j] * LOG2E);
    float accl = 0.f;   // accumulated log2 of renorm factors
    for (int c = 0; c < CC; ++c) {
        const float* M = ws_M + ((size_t)b * CC + c) * (VV * VV);
        float an = 0.f;
        #pragma unroll
        for (int i = 0; i < VV; ++i) {
            const float ai = __shfl(a, i, 32);
            an = __builtin_fmaf(ai, M[i * VV + j], an);
        }
        float mx = an;
        #pragma unroll
        for (int m = 16; m >= 1; m >>= 1) mx = fmaxf(mx, __shfl_xor(mx, m, 32));
        a = an / mx;
        accl += __builtin_amdgcn_logf(mx);   // v_log_f32 = log2
    }
    float rf = a * __builtin_amdgcn_exp2f(w_final[j] * LOG2E);
    float ss = rf;
    #pragma unroll
    for (int m = 16; m >= 1; m >>= 1) ss += __shfl_xor(ss, m, 32);
    const float denom_ln =
        (__builtin_amdgcn_logf(ss) + accl + SHIFT * (float)TT) * LN2f;

    if (lane == 0) {
        const float extra = w_init[tg[0]] + w_final[tg[TT]];
        out[b] = num + extra - denom_ln;
    }
}

extern "C" void kernel_launch(void* const* d_in, const int* in_sizes, int n_in,
                              void* d_out, int out_size, void* d_ws, size_t ws_size,
                              hipStream_t stream) {
    const float* scores  = (const float*)d_in[0];
    const int*   targets = (const int*)d_in[1];
    const float* w_tx    = (const float*)d_in[2];
    const float* w_init  = (const float*)d_in[3];
    const float* w_final = (const float*)d_in[4];
    const float* w_dur   = (const float*)d_in[5];
    float*       out     = (float*)d_out;
    float*       ws_M    = (float*)d_ws;   // BB*CC*32*32 fp32 = 2 MiB

    crf_chunk_kernel<<<BB * CC, 256, 0, stream>>>(scores, w_tx, w_dur, ws_M);
    crf_combine_kernel<<<BB, 64, 0, stream>>>(scores, targets, w_tx, w_init,
                                              w_final, w_dur, ws_M, out);
}